// Round 3
// baseline (1179.106 us; speedup 1.0000x reference)
//
#include <hip/hip_runtime.h>

static inline int cdiv(int a, int b) { return (a + b - 1) / b; }

// ---------------- degree + norm ----------------
__global__ __launch_bounds__(256) void k_deg(const int* __restrict__ dst, int E, int* __restrict__ deg) {
    int e = blockIdx.x * 256 + threadIdx.x;
    if (e < E) atomicAdd(&deg[dst[e]], 1);
}

__global__ __launch_bounds__(256) void k_dinv(const int* __restrict__ deg, float* __restrict__ dinv, int N) {
    int i = blockIdx.x * 256 + threadIdx.x;
    if (i < N) dinv[i] = rsqrtf((float)(deg[i] + 1));  // +1 self loop; always >= 1
}

// ---------------- exclusive scan (hierarchical) ----------------
#define SCAN_BS 1024

__global__ __launch_bounds__(SCAN_BS) void k_blocksum(const int* __restrict__ deg, int N, int* __restrict__ bsum) {
    __shared__ int s[SCAN_BS];
    int t = threadIdx.x;
    int i = blockIdx.x * SCAN_BS + t;
    s[t] = (i < N) ? deg[i] : 0;
    __syncthreads();
    for (int off = SCAN_BS / 2; off > 0; off >>= 1) {
        if (t < off) s[t] += s[t + off];
        __syncthreads();
    }
    if (t == 0) bsum[blockIdx.x] = s[0];
}

__global__ __launch_bounds__(128) void k_scan_bsums(const int* __restrict__ bsum, int NB, int* __restrict__ boff) {
    __shared__ int s[128];
    int t = threadIdx.x;
    int v = (t < NB) ? bsum[t] : 0;
    s[t] = v;
    __syncthreads();
    for (int off = 1; off < 128; off <<= 1) {
        int u = (t >= off) ? s[t - off] : 0;
        __syncthreads();
        s[t] += u;
        __syncthreads();
    }
    if (t < NB) boff[t] = s[t] - v;  // exclusive
}

__global__ __launch_bounds__(SCAN_BS) void k_scan_final(const int* __restrict__ deg, int N,
                                                        const int* __restrict__ boff,
                                                        int* __restrict__ offsets, int* __restrict__ cursor, int E) {
    __shared__ int s[SCAN_BS];
    int t = threadIdx.x;
    int i = blockIdx.x * SCAN_BS + t;
    int v = (i < N) ? deg[i] : 0;
    s[t] = v;
    __syncthreads();
    for (int off = 1; off < SCAN_BS; off <<= 1) {
        int u = (t >= off) ? s[t - off] : 0;
        __syncthreads();
        s[t] += u;
        __syncthreads();
    }
    if (i < N) {
        int ex = boff[blockIdx.x] + s[t] - v;
        offsets[i] = ex;
        cursor[i] = ex;
    }
    if (blockIdx.x == 0 && t == 0) offsets[N] = E;
}

// ---------------- CSR build (packed int2 {src, norm-as-bits}) ----------------
__global__ __launch_bounds__(256) void k_csr_build(const int* __restrict__ ei, int E,
                                                   const float* __restrict__ dinv,
                                                   int* __restrict__ cursor,
                                                   int2* __restrict__ csr) {
    int e = blockIdx.x * 256 + threadIdx.x;
    if (e >= E) return;
    int s = ei[e];
    int d = ei[E + e];
    int p = atomicAdd(&cursor[d], 1);
    float nrm = dinv[s] * dinv[d];
    csr[p] = make_int2(s, __float_as_int(nrm));
}

// ---------------- aggregation ----------------
template <int F>
__global__ __launch_bounds__(256) void k_agg(const float* __restrict__ feat,
                                             const int* __restrict__ offsets,
                                             const int2* __restrict__ csr,
                                             const float* __restrict__ dinv,
                                             float* __restrict__ out, int N) {
    int t = blockIdx.x * 256 + threadIdx.x;
    int g = t / F;
    int f = t & (F - 1);
    if (g >= N) return;
    int beg = offsets[g];
    int end = offsets[g + 1];
    float di = dinv[g];
    float acc = feat[g * F + f] * (di * di);
    int e = beg;
    for (; e + 8 <= end; e += 8) {
        int2 p0 = csr[e + 0], p1 = csr[e + 1], p2 = csr[e + 2], p3 = csr[e + 3];
        int2 p4 = csr[e + 4], p5 = csr[e + 5], p6 = csr[e + 6], p7 = csr[e + 7];
        float v0 = feat[p0.x * F + f];
        float v1 = feat[p1.x * F + f];
        float v2 = feat[p2.x * F + f];
        float v3 = feat[p3.x * F + f];
        float v4 = feat[p4.x * F + f];
        float v5 = feat[p5.x * F + f];
        float v6 = feat[p6.x * F + f];
        float v7 = feat[p7.x * F + f];
        acc = fmaf(v0, __int_as_float(p0.y), acc);
        acc = fmaf(v1, __int_as_float(p1.y), acc);
        acc = fmaf(v2, __int_as_float(p2.y), acc);
        acc = fmaf(v3, __int_as_float(p3.y), acc);
        acc = fmaf(v4, __int_as_float(p4.y), acc);
        acc = fmaf(v5, __int_as_float(p5.y), acc);
        acc = fmaf(v6, __int_as_float(p6.y), acc);
        acc = fmaf(v7, __int_as_float(p7.y), acc);
    }
    for (; e + 2 <= end; e += 2) {
        int2 p0 = csr[e + 0], p1 = csr[e + 1];
        float v0 = feat[p0.x * F + f];
        float v1 = feat[p1.x * F + f];
        acc = fmaf(v0, __int_as_float(p0.y), acc);
        acc = fmaf(v1, __int_as_float(p1.y), acc);
    }
    if (e < end) {
        int2 p0 = csr[e];
        acc = fmaf(feat[p0.x * F + f], __int_as_float(p0.y), acc);
    }
    out[g * F + f] = acc;
}

// ---------------- GEMM1: h2 = relu(A[Nx32] @ W[32x64] + b) ----------------
// block: 128 rows x 64 cols; 256 threads = 16(tm) x 16(tn); thread tile 8 rows x 4 cols.
__global__ __launch_bounds__(256) void k_gemm1(const float* __restrict__ A, const float* __restrict__ W,
                                               const float* __restrict__ b, float* __restrict__ out, int N) {
    __shared__ float sA[32][128];  // transposed: sA[k][row]
    __shared__ float sW[32][64];
    int tid = threadIdx.x;
    int row0 = blockIdx.x * 128;

    // stage W (2048 floats = 512 float4; 2 per thread)
    {
        const float4* Wv = (const float4*)W;
        float4* sWv = (float4*)&sW[0][0];
        sWv[tid] = Wv[tid];
        sWv[tid + 256] = Wv[tid + 256];
    }
    // stage A transposed: thread t handles row t/2, k-half (t&1)*16
    {
        int row = tid >> 1;
        int kh = (tid & 1) << 4;
        int gr = row0 + row;
        float4 v[4];
        if (gr < N) {
            const float4* src = (const float4*)(A + (size_t)gr * 32 + kh);
#pragma unroll
            for (int i = 0; i < 4; ++i) v[i] = src[i];
        } else {
#pragma unroll
            for (int i = 0; i < 4; ++i) v[i] = make_float4(0.f, 0.f, 0.f, 0.f);
        }
#pragma unroll
        for (int i = 0; i < 4; ++i) {
            const float* vp = (const float*)&v[i];
#pragma unroll
            for (int c = 0; c < 4; ++c) sA[kh + i * 4 + c][row] = vp[c];
        }
    }
    __syncthreads();

    int tm = tid >> 4, tn = tid & 15;
    float acc[8][4];
    {
        float4 bb = *(const float4*)(b + tn * 4);
        const float* bp = (const float*)&bb;
#pragma unroll
        for (int i = 0; i < 8; ++i)
#pragma unroll
            for (int j = 0; j < 4; ++j) acc[i][j] = bp[j];
    }
#pragma unroll
    for (int k = 0; k < 32; ++k) {
        float4 a0 = *(const float4*)&sA[k][tm * 8];
        float4 a1 = *(const float4*)&sA[k][tm * 8 + 4];
        float4 w0 = *(const float4*)&sW[k][tn * 4];
        const float* ap0 = (const float*)&a0;
        const float* ap1 = (const float*)&a1;
        const float* wp = (const float*)&w0;
#pragma unroll
        for (int i = 0; i < 4; ++i)
#pragma unroll
            for (int j = 0; j < 4; ++j) {
                acc[i][j] = fmaf(ap0[i], wp[j], acc[i][j]);
                acc[i + 4][j] = fmaf(ap1[i], wp[j], acc[i + 4][j]);
            }
    }
#pragma unroll
    for (int i = 0; i < 8; ++i) {
        int row = row0 + tm * 8 + i;
        if (row < N) {
            float4 o;
            o.x = fmaxf(acc[i][0], 0.f);
            o.y = fmaxf(acc[i][1], 0.f);
            o.z = fmaxf(acc[i][2], 0.f);
            o.w = fmaxf(acc[i][3], 0.f);
            *(float4*)(out + (size_t)row * 64 + tn * 4) = o;
        }
    }
}

// ---------------- GEMM2: out = A[Nx64] @ W[64x128] + b ----------------
// block: 128 rows x 128 cols; 256 threads = 16(tm) x 16(tn); thread tile 8x8.
__global__ __launch_bounds__(256) void k_gemm2(const float* __restrict__ A, const float* __restrict__ W,
                                               const float* __restrict__ b, float* __restrict__ out, int N) {
    __shared__ float sA[64][128];  // transposed: sA[k][row]  (32 KB)
    __shared__ float sW[64][128];  // as-is                    (32 KB)
    int tid = threadIdx.x;
    int row0 = blockIdx.x * 128;

    // stage W (8192 floats = 2048 float4; 8 per thread)
    {
        const float4* Wv = (const float4*)W;
        float4* sWv = (float4*)&sW[0][0];
#pragma unroll
        for (int i = 0; i < 8; ++i) sWv[tid + 256 * i] = Wv[tid + 256 * i];
    }
    // stage A transposed: thread t handles row t/2, k-half (t&1)*32
    {
        int row = tid >> 1;
        int kh = (tid & 1) << 5;
        int gr = row0 + row;
        float4 v[8];
        if (gr < N) {
            const float4* src = (const float4*)(A + (size_t)gr * 64 + kh);
#pragma unroll
            for (int i = 0; i < 8; ++i) v[i] = src[i];
        } else {
#pragma unroll
            for (int i = 0; i < 8; ++i) v[i] = make_float4(0.f, 0.f, 0.f, 0.f);
        }
#pragma unroll
        for (int i = 0; i < 8; ++i) {
            const float* vp = (const float*)&v[i];
#pragma unroll
            for (int c = 0; c < 4; ++c) sA[kh + i * 4 + c][row] = vp[c];
        }
    }
    __syncthreads();

    int tm = tid >> 4, tn = tid & 15;
    float acc[8][8];
    {
        float4 b0 = *(const float4*)(b + tn * 8);
        float4 b1 = *(const float4*)(b + tn * 8 + 4);
        const float* bp0 = (const float*)&b0;
        const float* bp1 = (const float*)&b1;
#pragma unroll
        for (int i = 0; i < 8; ++i) {
#pragma unroll
            for (int j = 0; j < 4; ++j) {
                acc[i][j] = bp0[j];
                acc[i][j + 4] = bp1[j];
            }
        }
    }
#pragma unroll
    for (int k = 0; k < 64; ++k) {
        float4 a0 = *(const float4*)&sA[k][tm * 8];
        float4 a1 = *(const float4*)&sA[k][tm * 8 + 4];
        float4 w0 = *(const float4*)&sW[k][tn * 8];
        float4 w1 = *(const float4*)&sW[k][tn * 8 + 4];
        const float* ap0 = (const float*)&a0;
        const float* ap1 = (const float*)&a1;
        const float* wp0 = (const float*)&w0;
        const float* wp1 = (const float*)&w1;
#pragma unroll
        for (int i = 0; i < 4; ++i)
#pragma unroll
            for (int j = 0; j < 4; ++j) {
                acc[i][j] = fmaf(ap0[i], wp0[j], acc[i][j]);
                acc[i][j + 4] = fmaf(ap0[i], wp1[j], acc[i][j + 4]);
                acc[i + 4][j] = fmaf(ap1[i], wp0[j], acc[i + 4][j]);
                acc[i + 4][j + 4] = fmaf(ap1[i], wp1[j], acc[i + 4][j + 4]);
            }
    }
#pragma unroll
    for (int i = 0; i < 8; ++i) {
        int row = row0 + tm * 8 + i;
        if (row < N) {
            *(float4*)(out + (size_t)row * 128 + tn * 8) = make_float4(acc[i][0], acc[i][1], acc[i][2], acc[i][3]);
            *(float4*)(out + (size_t)row * 128 + tn * 8 + 4) = make_float4(acc[i][4], acc[i][5], acc[i][6], acc[i][7]);
        }
    }
}

extern "C" void kernel_launch(void* const* d_in, const int* in_sizes, int n_in,
                              void* d_out, int out_size, void* d_ws, size_t ws_size,
                              hipStream_t stream) {
    const float* x  = (const float*)d_in[0];
    const int*   ei = (const int*)d_in[1];
    const float* W1 = (const float*)d_in[2];
    const float* b1 = (const float*)d_in[3];
    const float* W2 = (const float*)d_in[4];
    const float* b2 = (const float*)d_in[5];
    float* out = (float*)d_out;

    const int N = in_sizes[0] / 32;
    const int E = in_sizes[1] / 2;

    char* ws = (char*)d_ws;
    size_t off = 0;
    auto walloc = [&](size_t bytes) -> void* {
        void* p = ws + off;
        off = (off + bytes + 255) & ~(size_t)255;
        return p;
    };
    int*   deg     = (int*)  walloc((size_t)N * 4);
    float* dinv    = (float*)walloc((size_t)N * 4);
    int*   offsets = (int*)  walloc((size_t)(N + 1) * 4);
    int*   cursor  = (int*)  walloc((size_t)N * 4);
    int*   bsum    = (int*)  walloc(128 * 4);
    int*   boff    = (int*)  walloc(128 * 4);
    int2*  csr     = (int2*) walloc((size_t)E * 8);
    float* a1      = (float*)walloc((size_t)N * 32 * 4);
    float* h2      = (float*)walloc((size_t)N * 64 * 4);
    float* a2      = (float*)walloc((size_t)N * 64 * 4);
    (void)ws_size; (void)n_in; (void)out_size;

    hipMemsetAsync(deg, 0, (size_t)N * 4, stream);

    k_deg<<<cdiv(E, 256), 256, 0, stream>>>(ei + E, E, deg);
    k_dinv<<<cdiv(N, 256), 256, 0, stream>>>(deg, dinv, N);

    const int NB = cdiv(N, SCAN_BS);
    k_blocksum<<<NB, SCAN_BS, 0, stream>>>(deg, N, bsum);
    k_scan_bsums<<<1, 128, 0, stream>>>(bsum, NB, boff);
    k_scan_final<<<NB, SCAN_BS, 0, stream>>>(deg, N, boff, offsets, cursor, E);

    k_csr_build<<<cdiv(E, 256), 256, 0, stream>>>(ei, E, dinv, cursor, csr);

    k_agg<32><<<cdiv(N * 32, 256), 256, 0, stream>>>(x, offsets, csr, dinv, a1, N);
    k_gemm1<<<cdiv(N, 128), 256, 0, stream>>>(a1, W1, b1, h2, N);

    k_agg<64><<<cdiv(N * 64, 256), 256, 0, stream>>>(h2, offsets, csr, dinv, a2, N);
    k_gemm2<<<cdiv(N, 128), 256, 0, stream>>>(a2, W2, b2, out, N);
}

// Round 4
// 314.792 us; speedup vs baseline: 3.7457x; 3.7457x over previous
//
#include <hip/hip_runtime.h>

static inline int cdiv(int a, int b) { return (a + b - 1) / b; }

// ---------------- degree + norm ----------------
__global__ __launch_bounds__(256) void k_deg(const int* __restrict__ dst, int E, int* __restrict__ deg) {
    int e = blockIdx.x * 256 + threadIdx.x;
    if (e < E) atomicAdd(&deg[dst[e]], 1);
}

__global__ __launch_bounds__(256) void k_dinv(const int* __restrict__ deg, float* __restrict__ dinv, int N) {
    int i = blockIdx.x * 256 + threadIdx.x;
    if (i < N) dinv[i] = rsqrtf((float)(deg[i] + 1));  // +1 self loop; always >= 1
}

// ---------------- exclusive scan (hierarchical) ----------------
#define SCAN_BS 1024

__global__ __launch_bounds__(SCAN_BS) void k_blocksum(const int* __restrict__ deg, int N, int* __restrict__ bsum) {
    __shared__ int s[SCAN_BS];
    int t = threadIdx.x;
    int i = blockIdx.x * SCAN_BS + t;
    s[t] = (i < N) ? deg[i] : 0;
    __syncthreads();
    for (int off = SCAN_BS / 2; off > 0; off >>= 1) {
        if (t < off) s[t] += s[t + off];
        __syncthreads();
    }
    if (t == 0) bsum[blockIdx.x] = s[0];
}

__global__ __launch_bounds__(128) void k_scan_bsums(const int* __restrict__ bsum, int NB, int* __restrict__ boff) {
    __shared__ int s[128];
    int t = threadIdx.x;
    int v = (t < NB) ? bsum[t] : 0;
    s[t] = v;
    __syncthreads();
    for (int off = 1; off < 128; off <<= 1) {
        int u = (t >= off) ? s[t - off] : 0;
        __syncthreads();
        s[t] += u;
        __syncthreads();
    }
    if (t < NB) boff[t] = s[t] - v;  // exclusive
}

__global__ __launch_bounds__(SCAN_BS) void k_scan_final(const int* __restrict__ deg, int N,
                                                        const int* __restrict__ boff,
                                                        int* __restrict__ offsets, int* __restrict__ cursor, int E) {
    __shared__ int s[SCAN_BS];
    int t = threadIdx.x;
    int i = blockIdx.x * SCAN_BS + t;
    int v = (i < N) ? deg[i] : 0;
    s[t] = v;
    __syncthreads();
    for (int off = 1; off < SCAN_BS; off <<= 1) {
        int u = (t >= off) ? s[t - off] : 0;
        __syncthreads();
        s[t] += u;
        __syncthreads();
    }
    if (i < N) {
        int ex = boff[blockIdx.x] + s[t] - v;
        offsets[i] = ex;
        cursor[i] = ex;
    }
    if (blockIdx.x == 0 && t == 0) offsets[N] = E;
}

// ---------------- CSR build (packed int2 {src, norm-as-bits}) ----------------
__global__ __launch_bounds__(256) void k_csr_build(const int* __restrict__ ei, int E,
                                                   const float* __restrict__ dinv,
                                                   int* __restrict__ cursor,
                                                   int2* __restrict__ csr) {
    int e = blockIdx.x * 256 + threadIdx.x;
    if (e >= E) return;
    int s = ei[e];
    int d = ei[E + e];
    int p = atomicAdd(&cursor[d], 1);
    float nrm = dinv[s] * dinv[d];
    csr[p] = make_int2(s, __float_as_int(nrm));
}

// ---------------- aggregation ----------------
template <int F>
__global__ __launch_bounds__(256) void k_agg(const float* __restrict__ feat,
                                             const int* __restrict__ offsets,
                                             const int2* __restrict__ csr,
                                             const float* __restrict__ dinv,
                                             float* __restrict__ out, int N) {
    int t = blockIdx.x * 256 + threadIdx.x;
    int g = t / F;
    int f = t & (F - 1);
    if (g >= N) return;
    int beg = offsets[g];
    int end = offsets[g + 1];
    float di = dinv[g];
    float acc = feat[g * F + f] * (di * di);
    int e = beg;
    for (; e + 8 <= end; e += 8) {
        int2 p0 = csr[e + 0], p1 = csr[e + 1], p2 = csr[e + 2], p3 = csr[e + 3];
        int2 p4 = csr[e + 4], p5 = csr[e + 5], p6 = csr[e + 6], p7 = csr[e + 7];
        float v0 = feat[p0.x * F + f];
        float v1 = feat[p1.x * F + f];
        float v2 = feat[p2.x * F + f];
        float v3 = feat[p3.x * F + f];
        float v4 = feat[p4.x * F + f];
        float v5 = feat[p5.x * F + f];
        float v6 = feat[p6.x * F + f];
        float v7 = feat[p7.x * F + f];
        acc = fmaf(v0, __int_as_float(p0.y), acc);
        acc = fmaf(v1, __int_as_float(p1.y), acc);
        acc = fmaf(v2, __int_as_float(p2.y), acc);
        acc = fmaf(v3, __int_as_float(p3.y), acc);
        acc = fmaf(v4, __int_as_float(p4.y), acc);
        acc = fmaf(v5, __int_as_float(p5.y), acc);
        acc = fmaf(v6, __int_as_float(p6.y), acc);
        acc = fmaf(v7, __int_as_float(p7.y), acc);
    }
    for (; e + 2 <= end; e += 2) {
        int2 p0 = csr[e + 0], p1 = csr[e + 1];
        float v0 = feat[p0.x * F + f];
        float v1 = feat[p1.x * F + f];
        acc = fmaf(v0, __int_as_float(p0.y), acc);
        acc = fmaf(v1, __int_as_float(p1.y), acc);
    }
    if (e < end) {
        int2 p0 = csr[e];
        acc = fmaf(feat[p0.x * F + f], __int_as_float(p0.y), acc);
    }
    out[g * F + f] = acc;
}

// ---------------- GEMM1: h2 = relu(A[Nx32] @ W1[32x64] + b1) ----------------
// block: 64 rows x 64 cols; 256 threads; tm=tid&15 (4 rows), tn=tid>>4 (4 cols).
__global__ __launch_bounds__(256) void k_gemm1(const float* __restrict__ A, const float* __restrict__ W,
                                               const float* __restrict__ b, float* __restrict__ out, int N) {
    __shared__ float sA[32][68];   // sA[k][row], pad 68 -> staged writes 2-way, reads 2-way (free)
    __shared__ float sW[32][64];
    int tid = threadIdx.x;
    int row0 = blockIdx.x * 64;

    // stage W: 2048 floats = 512 float4, 2 per thread (contiguous -> conflict-free)
    {
        const float4* Wv = (const float4*)W;
        float4* sWv = (float4*)&sW[0][0];
        sWv[tid] = Wv[tid];
        sWv[tid + 256] = Wv[tid + 256];
    }
    // stage A transposed: thread -> row = tid>>2, k0 = (tid&3)*4 + 16*i  (i=0,1)
    {
        int row = tid >> 2;
        int gr = row0 + row;
        int kq = (tid & 3) * 4;
#pragma unroll
        for (int i = 0; i < 2; ++i) {
            int k0 = kq + 16 * i;
            float4 v = (gr < N) ? *(const float4*)(A + (size_t)gr * 32 + k0)
                                : make_float4(0.f, 0.f, 0.f, 0.f);
            sA[k0 + 0][row] = v.x;
            sA[k0 + 1][row] = v.y;
            sA[k0 + 2][row] = v.z;
            sA[k0 + 3][row] = v.w;
        }
    }
    __syncthreads();

    int tm = tid & 15, tn = tid >> 4;
    float acc[4][4];
#pragma unroll
    for (int i = 0; i < 4; ++i) {
        float4 bb = *(const float4*)(b + tn * 4);
        acc[i][0] = bb.x; acc[i][1] = bb.y; acc[i][2] = bb.z; acc[i][3] = bb.w;
    }
#pragma unroll 4
    for (int k = 0; k < 32; ++k) {
        float4 a = *(const float4*)&sA[k][tm * 4];
        float4 w = *(const float4*)&sW[k][tn * 4];
        float av[4] = {a.x, a.y, a.z, a.w};
        float wv[4] = {w.x, w.y, w.z, w.w};
#pragma unroll
        for (int i = 0; i < 4; ++i)
#pragma unroll
            for (int j = 0; j < 4; ++j) acc[i][j] = fmaf(av[i], wv[j], acc[i][j]);
    }
#pragma unroll
    for (int i = 0; i < 4; ++i) {
        int row = row0 + tm * 4 + i;
        if (row < N) {
            float4 o;
            o.x = fmaxf(acc[i][0], 0.f);
            o.y = fmaxf(acc[i][1], 0.f);
            o.z = fmaxf(acc[i][2], 0.f);
            o.w = fmaxf(acc[i][3], 0.f);
            *(float4*)(out + (size_t)row * 64 + tn * 4) = o;
        }
    }
}

// ---------------- GEMM2: out = A[Nx64] @ W2[64x128] + b2 ----------------
// block: 64 rows x 128 cols; 256 threads; tm=tid&15 (4 rows), tn=tid>>4 (8 cols).
__global__ __launch_bounds__(256) void k_gemm2(const float* __restrict__ A, const float* __restrict__ W,
                                               const float* __restrict__ b, float* __restrict__ out, int N) {
    __shared__ float sA[64][68];   // 17.4 KB
    __shared__ float sW[64][128];  // 32 KB
    int tid = threadIdx.x;
    int row0 = blockIdx.x * 64;

    // stage W: 8192 floats = 2048 float4, 8 per thread (contiguous)
    {
        const float4* Wv = (const float4*)W;
        float4* sWv = (float4*)&sW[0][0];
#pragma unroll
        for (int i = 0; i < 8; ++i) sWv[tid + 256 * i] = Wv[tid + 256 * i];
    }
    // stage A transposed: thread -> row = tid>>2, k0 = (tid&3)*4 + 16*i (i=0..3)
    {
        int row = tid >> 2;
        int gr = row0 + row;
        int kq = (tid & 3) * 4;
#pragma unroll
        for (int i = 0; i < 4; ++i) {
            int k0 = kq + 16 * i;
            float4 v = (gr < N) ? *(const float4*)(A + (size_t)gr * 64 + k0)
                                : make_float4(0.f, 0.f, 0.f, 0.f);
            sA[k0 + 0][row] = v.x;
            sA[k0 + 1][row] = v.y;
            sA[k0 + 2][row] = v.z;
            sA[k0 + 3][row] = v.w;
        }
    }
    __syncthreads();

    int tm = tid & 15, tn = tid >> 4;
    float acc[4][8];
    {
        float4 b0 = *(const float4*)(b + tn * 8);
        float4 b1 = *(const float4*)(b + tn * 8 + 4);
#pragma unroll
        for (int i = 0; i < 4; ++i) {
            acc[i][0] = b0.x; acc[i][1] = b0.y; acc[i][2] = b0.z; acc[i][3] = b0.w;
            acc[i][4] = b1.x; acc[i][5] = b1.y; acc[i][6] = b1.z; acc[i][7] = b1.w;
        }
    }
#pragma unroll 4
    for (int k = 0; k < 64; ++k) {
        float4 a = *(const float4*)&sA[k][tm * 4];
        float4 w0 = *(const float4*)&sW[k][tn * 8];
        float4 w1 = *(const float4*)&sW[k][tn * 8 + 4];
        float av[4] = {a.x, a.y, a.z, a.w};
        float wv[8] = {w0.x, w0.y, w0.z, w0.w, w1.x, w1.y, w1.z, w1.w};
#pragma unroll
        for (int i = 0; i < 4; ++i)
#pragma unroll
            for (int j = 0; j < 8; ++j) acc[i][j] = fmaf(av[i], wv[j], acc[i][j]);
    }
#pragma unroll
    for (int i = 0; i < 4; ++i) {
        int row = row0 + tm * 4 + i;
        if (row < N) {
            *(float4*)(out + (size_t)row * 128 + tn * 8) =
                make_float4(acc[i][0], acc[i][1], acc[i][2], acc[i][3]);
            *(float4*)(out + (size_t)row * 128 + tn * 8 + 4) =
                make_float4(acc[i][4], acc[i][5], acc[i][6], acc[i][7]);
        }
    }
}

extern "C" void kernel_launch(void* const* d_in, const int* in_sizes, int n_in,
                              void* d_out, int out_size, void* d_ws, size_t ws_size,
                              hipStream_t stream) {
    const float* x  = (const float*)d_in[0];
    const int*   ei = (const int*)d_in[1];
    const float* W1 = (const float*)d_in[2];
    const float* b1 = (const float*)d_in[3];
    const float* W2 = (const float*)d_in[4];
    const float* b2 = (const float*)d_in[5];
    float* out = (float*)d_out;

    const int N = in_sizes[0] / 32;
    const int E = in_sizes[1] / 2;

    char* ws = (char*)d_ws;
    size_t off = 0;
    auto walloc = [&](size_t bytes) -> void* {
        void* p = ws + off;
        off = (off + bytes + 255) & ~(size_t)255;
        return p;
    };
    int*   deg     = (int*)  walloc((size_t)N * 4);
    float* dinv    = (float*)walloc((size_t)N * 4);
    int*   offsets = (int*)  walloc((size_t)(N + 1) * 4);
    int*   cursor  = (int*)  walloc((size_t)N * 4);
    int*   bsum    = (int*)  walloc(128 * 4);
    int*   boff    = (int*)  walloc(128 * 4);
    int2*  csr     = (int2*) walloc((size_t)E * 8);
    float* a1      = (float*)walloc((size_t)N * 32 * 4);
    float* h2      = (float*)walloc((size_t)N * 64 * 4);
    float* a2      = (float*)walloc((size_t)N * 64 * 4);
    (void)ws_size; (void)n_in; (void)out_size;

    hipMemsetAsync(deg, 0, (size_t)N * 4, stream);

    k_deg<<<cdiv(E, 256), 256, 0, stream>>>(ei + E, E, deg);
    k_dinv<<<cdiv(N, 256), 256, 0, stream>>>(deg, dinv, N);

    const int NB = cdiv(N, SCAN_BS);
    k_blocksum<<<NB, SCAN_BS, 0, stream>>>(deg, N, bsum);
    k_scan_bsums<<<1, 128, 0, stream>>>(bsum, NB, boff);
    k_scan_final<<<NB, SCAN_BS, 0, stream>>>(deg, N, boff, offsets, cursor, E);

    k_csr_build<<<cdiv(E, 256), 256, 0, stream>>>(ei, E, dinv, cursor, csr);

    k_agg<32><<<cdiv(N * 32, 256), 256, 0, stream>>>(x, offsets, csr, dinv, a1, N);
    k_gemm1<<<cdiv(N, 64), 256, 0, stream>>>(a1, W1, b1, h2, N);

    k_agg<64><<<cdiv(N * 64, 256), 256, 0, stream>>>(h2, offsets, csr, dinv, a2, N);
    k_gemm2<<<cdiv(N, 64), 256, 0, stream>>>(a2, W2, b2, out, N);
}

// Round 5
// 251.719 us; speedup vs baseline: 4.6842x; 1.2506x over previous
//
#include <hip/hip_runtime.h>

static inline int cdiv(int a, int b) { return (a + b - 1) / b; }

// ---------------- pass 1: degree + per-edge rank ----------------
__global__ __launch_bounds__(256) void k_deg_rank(const int* __restrict__ dst, int E,
                                                  int* __restrict__ deg, unsigned short* __restrict__ rank) {
    int e = blockIdx.x * 256 + threadIdx.x;
    if (e < E) {
        int d = dst[e];
        int r = atomicAdd(&deg[d], 1);
        rank[e] = (unsigned short)r;
    }
}

__global__ __launch_bounds__(256) void k_dinv(const int* __restrict__ deg, float* __restrict__ dinv, int N) {
    int i = blockIdx.x * 256 + threadIdx.x;
    if (i < N) dinv[i] = rsqrtf((float)(deg[i] + 1));  // +1 self loop; always >= 1
}

// ---------------- exclusive scan (hierarchical) ----------------
#define SCAN_BS 1024

__global__ __launch_bounds__(SCAN_BS) void k_blocksum(const int* __restrict__ deg, int N, int* __restrict__ bsum) {
    __shared__ int s[SCAN_BS];
    int t = threadIdx.x;
    int i = blockIdx.x * SCAN_BS + t;
    s[t] = (i < N) ? deg[i] : 0;
    __syncthreads();
    for (int off = SCAN_BS / 2; off > 0; off >>= 1) {
        if (t < off) s[t] += s[t + off];
        __syncthreads();
    }
    if (t == 0) bsum[blockIdx.x] = s[0];
}

__global__ __launch_bounds__(128) void k_scan_bsums(const int* __restrict__ bsum, int NB, int* __restrict__ boff) {
    __shared__ int s[128];
    int t = threadIdx.x;
    int v = (t < NB) ? bsum[t] : 0;
    s[t] = v;
    __syncthreads();
    for (int off = 1; off < 128; off <<= 1) {
        int u = (t >= off) ? s[t - off] : 0;
        __syncthreads();
        s[t] += u;
        __syncthreads();
    }
    if (t < NB) boff[t] = s[t] - v;  // exclusive
}

__global__ __launch_bounds__(SCAN_BS) void k_scan_final(const int* __restrict__ deg, int N,
                                                        const int* __restrict__ boff,
                                                        int* __restrict__ offsets, int E) {
    __shared__ int s[SCAN_BS];
    int t = threadIdx.x;
    int i = blockIdx.x * SCAN_BS + t;
    int v = (i < N) ? deg[i] : 0;
    s[t] = v;
    __syncthreads();
    for (int off = 1; off < SCAN_BS; off <<= 1) {
        int u = (t >= off) ? s[t - off] : 0;
        __syncthreads();
        s[t] += u;
        __syncthreads();
    }
    if (i < N) offsets[i] = boff[blockIdx.x] + s[t] - v;
    if (blockIdx.x == 0 && t == 0) offsets[N] = E;
}

// ---------------- pass 2: CSR scatter (no atomics; 4B entries) ----------------
__global__ __launch_bounds__(256) void k_csr_build(const int* __restrict__ ei, int E,
                                                   const int* __restrict__ offsets,
                                                   const unsigned short* __restrict__ rank,
                                                   int* __restrict__ csr_src) {
    int e = blockIdx.x * 256 + threadIdx.x;
    if (e >= E) return;
    int s = ei[e];
    int d = ei[E + e];
    int p = offsets[d] + (int)rank[e];
    csr_src[p] = s;
}

// ---------------- aggregation: out[g] = dinv[g]*( feat[g]*dinv[g] + sum feat[s]*dinv[s] ) ----------------
template <int F>
__global__ __launch_bounds__(256) void k_agg(const float* __restrict__ feat,
                                             const int* __restrict__ offsets,
                                             const int* __restrict__ csr_src,
                                             const float* __restrict__ dinv,
                                             float* __restrict__ out, int N) {
    int t = blockIdx.x * 256 + threadIdx.x;
    int g = t / F;
    int f = t & (F - 1);
    if (g >= N) return;
    int beg = offsets[g];
    int end = offsets[g + 1];
    float di = dinv[g];
    float acc = feat[g * F + f] * di;  // self term (final *di makes it di^2)
    int e = beg;
    for (; e + 8 <= end; e += 8) {
        int s0 = csr_src[e + 0], s1 = csr_src[e + 1], s2 = csr_src[e + 2], s3 = csr_src[e + 3];
        int s4 = csr_src[e + 4], s5 = csr_src[e + 5], s6 = csr_src[e + 6], s7 = csr_src[e + 7];
        float w0 = dinv[s0], w1 = dinv[s1], w2 = dinv[s2], w3 = dinv[s3];
        float w4 = dinv[s4], w5 = dinv[s5], w6 = dinv[s6], w7 = dinv[s7];
        float v0 = feat[s0 * F + f];
        float v1 = feat[s1 * F + f];
        float v2 = feat[s2 * F + f];
        float v3 = feat[s3 * F + f];
        float v4 = feat[s4 * F + f];
        float v5 = feat[s5 * F + f];
        float v6 = feat[s6 * F + f];
        float v7 = feat[s7 * F + f];
        acc = fmaf(v0, w0, acc);
        acc = fmaf(v1, w1, acc);
        acc = fmaf(v2, w2, acc);
        acc = fmaf(v3, w3, acc);
        acc = fmaf(v4, w4, acc);
        acc = fmaf(v5, w5, acc);
        acc = fmaf(v6, w6, acc);
        acc = fmaf(v7, w7, acc);
    }
    for (; e + 2 <= end; e += 2) {
        int s0 = csr_src[e + 0], s1 = csr_src[e + 1];
        float w0 = dinv[s0], w1 = dinv[s1];
        float v0 = feat[s0 * F + f];
        float v1 = feat[s1 * F + f];
        acc = fmaf(v0, w0, acc);
        acc = fmaf(v1, w1, acc);
    }
    if (e < end) {
        int s0 = csr_src[e];
        acc = fmaf(feat[s0 * F + f], dinv[s0], acc);
    }
    out[g * F + f] = acc * di;
}

// ---------------- GEMM1: h2 = relu(A[Nx32] @ W1[32x64] + b1) ----------------
__global__ __launch_bounds__(256) void k_gemm1(const float* __restrict__ A, const float* __restrict__ W,
                                               const float* __restrict__ b, float* __restrict__ out, int N) {
    __shared__ float sA[32][68];
    __shared__ float sW[32][64];
    int tid = threadIdx.x;
    int row0 = blockIdx.x * 64;

    {
        const float4* Wv = (const float4*)W;
        float4* sWv = (float4*)&sW[0][0];
        sWv[tid] = Wv[tid];
        sWv[tid + 256] = Wv[tid + 256];
    }
    {
        int row = tid >> 2;
        int gr = row0 + row;
        int kq = (tid & 3) * 4;
#pragma unroll
        for (int i = 0; i < 2; ++i) {
            int k0 = kq + 16 * i;
            float4 v = (gr < N) ? *(const float4*)(A + (size_t)gr * 32 + k0)
                                : make_float4(0.f, 0.f, 0.f, 0.f);
            sA[k0 + 0][row] = v.x;
            sA[k0 + 1][row] = v.y;
            sA[k0 + 2][row] = v.z;
            sA[k0 + 3][row] = v.w;
        }
    }
    __syncthreads();

    int tm = tid & 15, tn = tid >> 4;
    float acc[4][4];
#pragma unroll
    for (int i = 0; i < 4; ++i) {
        float4 bb = *(const float4*)(b + tn * 4);
        acc[i][0] = bb.x; acc[i][1] = bb.y; acc[i][2] = bb.z; acc[i][3] = bb.w;
    }
#pragma unroll 4
    for (int k = 0; k < 32; ++k) {
        float4 a = *(const float4*)&sA[k][tm * 4];
        float4 w = *(const float4*)&sW[k][tn * 4];
        float av[4] = {a.x, a.y, a.z, a.w};
        float wv[4] = {w.x, w.y, w.z, w.w};
#pragma unroll
        for (int i = 0; i < 4; ++i)
#pragma unroll
            for (int j = 0; j < 4; ++j) acc[i][j] = fmaf(av[i], wv[j], acc[i][j]);
    }
#pragma unroll
    for (int i = 0; i < 4; ++i) {
        int row = row0 + tm * 4 + i;
        if (row < N) {
            float4 o;
            o.x = fmaxf(acc[i][0], 0.f);
            o.y = fmaxf(acc[i][1], 0.f);
            o.z = fmaxf(acc[i][2], 0.f);
            o.w = fmaxf(acc[i][3], 0.f);
            *(float4*)(out + (size_t)row * 64 + tn * 4) = o;
        }
    }
}

// ---------------- GEMM2: out = A[Nx64] @ W2[64x128] + b2 ----------------
__global__ __launch_bounds__(256) void k_gemm2(const float* __restrict__ A, const float* __restrict__ W,
                                               const float* __restrict__ b, float* __restrict__ out, int N) {
    __shared__ float sA[64][68];
    __shared__ float sW[64][128];
    int tid = threadIdx.x;
    int row0 = blockIdx.x * 64;

    {
        const float4* Wv = (const float4*)W;
        float4* sWv = (float4*)&sW[0][0];
#pragma unroll
        for (int i = 0; i < 8; ++i) sWv[tid + 256 * i] = Wv[tid + 256 * i];
    }
    {
        int row = tid >> 2;
        int gr = row0 + row;
        int kq = (tid & 3) * 4;
#pragma unroll
        for (int i = 0; i < 4; ++i) {
            int k0 = kq + 16 * i;
            float4 v = (gr < N) ? *(const float4*)(A + (size_t)gr * 64 + k0)
                                : make_float4(0.f, 0.f, 0.f, 0.f);
            sA[k0 + 0][row] = v.x;
            sA[k0 + 1][row] = v.y;
            sA[k0 + 2][row] = v.z;
            sA[k0 + 3][row] = v.w;
        }
    }
    __syncthreads();

    int tm = tid & 15, tn = tid >> 4;
    float acc[4][8];
    {
        float4 b0 = *(const float4*)(b + tn * 8);
        float4 b1 = *(const float4*)(b + tn * 8 + 4);
#pragma unroll
        for (int i = 0; i < 4; ++i) {
            acc[i][0] = b0.x; acc[i][1] = b0.y; acc[i][2] = b0.z; acc[i][3] = b0.w;
            acc[i][4] = b1.x; acc[i][5] = b1.y; acc[i][6] = b1.z; acc[i][7] = b1.w;
        }
    }
#pragma unroll 4
    for (int k = 0; k < 64; ++k) {
        float4 a = *(const float4*)&sA[k][tm * 4];
        float4 w0 = *(const float4*)&sW[k][tn * 8];
        float4 w1 = *(const float4*)&sW[k][tn * 8 + 4];
        float av[4] = {a.x, a.y, a.z, a.w};
        float wv[8] = {w0.x, w0.y, w0.z, w0.w, w1.x, w1.y, w1.z, w1.w};
#pragma unroll
        for (int i = 0; i < 4; ++i)
#pragma unroll
            for (int j = 0; j < 8; ++j) acc[i][j] = fmaf(av[i], wv[j], acc[i][j]);
    }
#pragma unroll
    for (int i = 0; i < 4; ++i) {
        int row = row0 + tm * 4 + i;
        if (row < N) {
            *(float4*)(out + (size_t)row * 128 + tn * 8) =
                make_float4(acc[i][0], acc[i][1], acc[i][2], acc[i][3]);
            *(float4*)(out + (size_t)row * 128 + tn * 8 + 4) =
                make_float4(acc[i][4], acc[i][5], acc[i][6], acc[i][7]);
        }
    }
}

extern "C" void kernel_launch(void* const* d_in, const int* in_sizes, int n_in,
                              void* d_out, int out_size, void* d_ws, size_t ws_size,
                              hipStream_t stream) {
    const float* x  = (const float*)d_in[0];
    const int*   ei = (const int*)d_in[1];
    const float* W1 = (const float*)d_in[2];
    const float* b1 = (const float*)d_in[3];
    const float* W2 = (const float*)d_in[4];
    const float* b2 = (const float*)d_in[5];
    float* out = (float*)d_out;

    const int N = in_sizes[0] / 32;
    const int E = in_sizes[1] / 2;

    char* ws = (char*)d_ws;
    size_t off = 0;
    auto walloc = [&](size_t bytes) -> void* {
        void* p = ws + off;
        off = (off + bytes + 255) & ~(size_t)255;
        return p;
    };
    int*            deg     = (int*)            walloc((size_t)N * 4);
    float*          dinv    = (float*)          walloc((size_t)N * 4);
    int*            offsets = (int*)            walloc((size_t)(N + 1) * 4);
    int*            bsum    = (int*)            walloc(128 * 4);
    int*            boff    = (int*)            walloc(128 * 4);
    unsigned short* rank    = (unsigned short*) walloc((size_t)E * 2);
    int*            csr_src = (int*)            walloc((size_t)E * 4);
    float*          a1      = (float*)          walloc((size_t)N * 32 * 4);
    float*          h2      = (float*)          walloc((size_t)N * 64 * 4);
    float*          a2      = (float*)          walloc((size_t)N * 64 * 4);
    (void)ws_size; (void)n_in; (void)out_size;

    hipMemsetAsync(deg, 0, (size_t)N * 4, stream);

    k_deg_rank<<<cdiv(E, 256), 256, 0, stream>>>(ei + E, E, deg, rank);
    k_dinv<<<cdiv(N, 256), 256, 0, stream>>>(deg, dinv, N);

    const int NB = cdiv(N, SCAN_BS);
    k_blocksum<<<NB, SCAN_BS, 0, stream>>>(deg, N, bsum);
    k_scan_bsums<<<1, 128, 0, stream>>>(bsum, NB, boff);
    k_scan_final<<<NB, SCAN_BS, 0, stream>>>(deg, N, boff, offsets, E);

    k_csr_build<<<cdiv(E, 256), 256, 0, stream>>>(ei, E, offsets, rank, csr_src);

    k_agg<32><<<cdiv(N * 32, 256), 256, 0, stream>>>(x, offsets, csr_src, dinv, a1, N);
    k_gemm1<<<cdiv(N, 64), 256, 0, stream>>>(a1, W1, b1, h2, N);

    k_agg<64><<<cdiv(N * 64, 256), 256, 0, stream>>>(h2, offsets, csr_src, dinv, a2, N);
    k_gemm2<<<cdiv(N, 64), 256, 0, stream>>>(a2, W2, b2, out, N);
}